// Round 22
// baseline (419.364 us; speedup 1.0000x reference)
//
#include <hip/hip_runtime.h>
#include <hip/hip_bf16.h>
#include <math.h>

#define BB 4
#define SS 2048
#define DIN 768
#define HH 12
#define DH 64
#define NT (SS / 64)

typedef __attribute__((ext_vector_type(8))) _Float16 f16x8;
typedef __attribute__((ext_vector_type(4))) _Float16 f16x4;
typedef __attribute__((ext_vector_type(2))) _Float16 f16x2;
typedef __attribute__((ext_vector_type(4))) float f32x4;
typedef __attribute__((ext_vector_type(16))) float f32x16;
typedef __attribute__((ext_vector_type(4))) unsigned u32x4;

// split fp32 -> fp16 hi + fp16 lo (v ~= hi+lo, |lo| <= 2^-11 |v|)
// r16 lesson: ALL lo-terms required (shared-mode error -> absmax 832).
// r20 lesson: LDS staging is a COALESCING transformer — per-lane direct
// B-frag loads touch 16 cache lines/instr and lose 2x (124->270us).
__device__ inline void splith(float v, _Float16& hi, _Float16& lo) {
    hi = (_Float16)v;
    lo = (_Float16)(v - (float)hi);
}
__device__ inline unsigned packh2(float a, float b) {
    f16x2 h; h[0] = (_Float16)a; h[1] = (_Float16)b;
    return __builtin_bit_cast(unsigned, h);
}
// 16B fp16 fragment via two 8B LDS reads (stride-68 rows are only 8B-aligned)
__device__ inline f16x8 ldb64x2(const _Float16* p) {
    const uint2* q = reinterpret_cast<const uint2*>(p);
    uint2 a = q[0], b = q[1];
    u32x4 u = {a.x, a.y, b.x, b.y};
    return __builtin_bit_cast(f16x8, u);
}
__device__ inline void stb64x2(_Float16* p, uint4 v) {
    uint2* q = reinterpret_cast<uint2*>(p);
    q[0] = make_uint2(v.x, v.y);
    q[1] = make_uint2(v.z, v.w);
}
__device__ inline f32x16 zero16() {
    f32x16 v;
    #pragma unroll
    for (int i = 0; i < 16; ++i) v[i] = 0.f;
    return v;
}

// ---------------------------------------------------------------
// prep (merged, one dispatch): [0,432) W split+transpose;
// [432,456) wc split; [456,3528) x -> fp16 hi AND lo.
// ---------------------------------------------------------------
__global__ __launch_bounds__(256) void prep_kernel(
    const float* __restrict__ x,
    const float* __restrict__ wq, const float* __restrict__ wk, const float* __restrict__ wv,
    const float* __restrict__ wc,
    _Float16* __restrict__ whi, _Float16* __restrict__ wlo,
    _Float16* __restrict__ wch, _Float16* __restrict__ wcl,
    _Float16* __restrict__ xh, _Float16* __restrict__ xl)
{
    __shared__ float tile[64][65];
    const int bid = blockIdx.x;
    const int t = threadIdx.x;

    if (bid < 432) {        // ---- W: [h][k][n] fp32 -> [plane][n][k] fp16 hi/lo
        const int kt = bid % 12, h = (bid / 12) % 12, which = bid / 144;
        const float* w = (which == 0) ? wq : (which == 1) ? wk : wv;
        w += (size_t)h * (DIN * DH);
        const size_t plane = ((size_t)which * HH + h) * (size_t)(64 * DIN);
        {
            int r = t >> 2, n0 = (t & 3) * 16;
            const float* src = w + (size_t)(kt * 64 + r) * DH + n0;
            #pragma unroll
            for (int q = 0; q < 4; ++q) {
                float4 v = *reinterpret_cast<const float4*>(src + q * 4);
                tile[r][n0 + q * 4 + 0] = v.x; tile[r][n0 + q * 4 + 1] = v.y;
                tile[r][n0 + q * 4 + 2] = v.z; tile[r][n0 + q * 4 + 3] = v.w;
            }
        }
        __syncthreads();
        {
            int n = t >> 2, k0 = (t & 3) * 16;
            f16x8 h0, h1, l0, l1;
            #pragma unroll
            for (int j = 0; j < 8; ++j) {
                _Float16 hh, ll;
                splith(tile[k0 + j][n], hh, ll);     h0[j] = hh; l0[j] = ll;
                splith(tile[k0 + 8 + j][n], hh, ll); h1[j] = hh; l1[j] = ll;
            }
            size_t base = plane + (size_t)n * DIN + kt * 64 + k0;
            *reinterpret_cast<f16x8*>(whi + base)     = h0;
            *reinterpret_cast<f16x8*>(whi + base + 8) = h1;
            *reinterpret_cast<f16x8*>(wlo + base)     = l0;
            *reinterpret_cast<f16x8*>(wlo + base + 8) = l1;
        }
    } else if (bid < 456) { // ---- wc split
        int idx = ((bid - 432) * 256 + t) * 8;
        float4 a = *reinterpret_cast<const float4*>(wc + idx);
        float4 b = *reinterpret_cast<const float4*>(wc + idx + 4);
        float f[8] = {a.x, a.y, a.z, a.w, b.x, b.y, b.z, b.w};
        f16x8 hv, lv;
        #pragma unroll
        for (int j = 0; j < 8; ++j) {
            _Float16 hh, ll;
            splith(f[j], hh, ll);
            hv[j] = hh; lv[j] = ll;
        }
        *reinterpret_cast<f16x8*>(wch + idx) = hv;
        *reinterpret_cast<f16x8*>(wcl + idx) = lv;
    } else {                // ---- x -> fp16 hi + lo
        int idx = ((bid - 456) * 256 + t) * 8;
        float4 a = *reinterpret_cast<const float4*>(x + idx);
        float4 b = *reinterpret_cast<const float4*>(x + idx + 4);
        float f[8] = {a.x, a.y, a.z, a.w, b.x, b.y, b.z, b.w};
        f16x8 hv, lv;
        #pragma unroll
        for (int j = 0; j < 8; ++j) {
            _Float16 hh, ll;
            splith(f[j], hh, ll);
            hv[j] = hh; lv[j] = ll;
        }
        *reinterpret_cast<f16x8*>(xh + idx) = hv;
        *reinterpret_cast<f16x8*>(xl + idx) = lv;
    }
}

// ---------------------------------------------------------------
// qkv_proj v12: BM=256 — each wave owns 4 A-row-groups so every
// B-frag LDS read feeds 4 MFMAs; LDS ops/MFMA 0.75 -> 0.54 (-28%).
// Same r19 schedule: x+w LDS-staged, all 10 staging uint4
// reg-prefetched one k-tile ahead. 3-term split (bit-identical math).
// LDS 50 KB (xbuf 40 + w 10) -> 3 blocks/CU. SPILL SENTINEL: ~62MB.
// grid 1152 = 8 xcd x 4 mt(256-row) x 36 planes.
// ---------------------------------------------------------------
__global__ __launch_bounds__(256) void qkv_proj_kernel(
    const _Float16* __restrict__ xh, const _Float16* __restrict__ xl,
    const _Float16* __restrict__ whi, const _Float16* __restrict__ wlo,
    _Float16* __restrict__ qh, _Float16* __restrict__ ql,
    _Float16* __restrict__ kh, _Float16* __restrict__ kl,
    _Float16* __restrict__ vt)
{
    const int flat = blockIdx.x;
    const int xcd  = flat & 7;
    const int rest = flat >> 3;             // 0..143
    const int mt   = xcd * 4 + (rest & 3);  // 0..31 (256-row tiles)
    const int hw   = rest >> 2;             // 0..35
    const int which = hw / HH, h = hw % HH;
    const int m0 = mt * 256;
    const size_t wplane = ((size_t)which * HH + h) * (size_t)(64 * DIN);

    // xbuf: [0..10239] = xsh[256][40], [10240..20479] = xsl[256][40];
    // epilogue vtile[64][264] (16896 elems) overlays xbuf.
    __shared__ _Float16 xbuf[20480];
    __shared__ _Float16 wsh[64][40], wsl[64][40];

    const int t = threadIdx.x;
    const int lane = t & 63, wid = t >> 6;
    const int fr = lane & 15, fg = lane >> 4, g8 = fg * 8;
    const int rx4 = t >> 2, cx4 = (t & 3) * 8;   // x-staging: 4 lanes/row, 16B each
    const int rw = t >> 2, c8 = (t & 3) * 8;     // w-staging ownership

    f32x4 acc[4][4];
    #pragma unroll
    for (int g = 0; g < 4; ++g)
        #pragma unroll
        for (int n = 0; n < 4; ++n) acc[g][n] = (f32x4){0.f, 0.f, 0.f, 0.f};

    uint4 phx[4], plx[4], pwh, pwl;
    auto pre = [&](int ks) {
        #pragma unroll
        for (int p = 0; p < 4; ++p) {
            const size_t xb = (size_t)(m0 + p * 64 + rx4) * DIN + ks * 32 + cx4;
            phx[p] = *reinterpret_cast<const uint4*>(xh + xb);
            plx[p] = *reinterpret_cast<const uint4*>(xl + xb);
        }
        const size_t wb = wplane + (size_t)rw * DIN + ks * 32 + c8;
        pwh = *reinterpret_cast<const uint4*>(whi + wb);
        pwl = *reinterpret_cast<const uint4*>(wlo + wb);
    };
    pre(0);

    for (int ks = 0; ks < DIN / 32; ++ks) {
        __syncthreads();   // prior MFMA phase done reading LDS
        #pragma unroll
        for (int p = 0; p < 4; ++p) {
            *reinterpret_cast<uint4*>(&xbuf[(p * 64 + rx4) * 40 + cx4])         = phx[p];
            *reinterpret_cast<uint4*>(&xbuf[10240 + (p * 64 + rx4) * 40 + cx4]) = plx[p];
        }
        *reinterpret_cast<uint4*>(&wsh[rw][c8]) = pwh;
        *reinterpret_cast<uint4*>(&wsl[rw][c8]) = pwl;
        if (ks + 1 < DIN / 32) pre(ks + 1);   // drains under MFMA below
        __syncthreads();   // tile ready

        f16x8 ah[4], al[4];
        #pragma unroll
        for (int g = 0; g < 4; ++g) {
            const int row = wid * 64 + g * 16 + fr;
            ah[g] = *reinterpret_cast<const f16x8*>(&xbuf[row * 40 + g8]);
            al[g] = *reinterpret_cast<const f16x8*>(&xbuf[10240 + row * 40 + g8]);
        }
        #pragma unroll
        for (int n = 0; n < 4; ++n) {
            f16x8 bh = *reinterpret_cast<const f16x8*>(&wsh[n * 16 + fr][g8]);
            f16x8 bl = *reinterpret_cast<const f16x8*>(&wsl[n * 16 + fr][g8]);
            #pragma unroll
            for (int g = 0; g < 4; ++g) {
                acc[g][n] = __builtin_amdgcn_mfma_f32_16x16x32_f16(ah[g], bh, acc[g][n], 0, 0, 0);
                acc[g][n] = __builtin_amdgcn_mfma_f32_16x16x32_f16(ah[g], bl, acc[g][n], 0, 0, 0);
                acc[g][n] = __builtin_amdgcn_mfma_f32_16x16x32_f16(al[g], bh, acc[g][n], 0, 0, 0);
            }
        }
    }

    const int b0 = m0 >> 11, s0 = m0 & 2047;   // 256-row tile stays within one batch
    if (which == 2) {
        // V -> vtile[d][s_local 0..255] (overlays xbuf) then vector row-stores
        __syncthreads();   // all waves done reading xbuf in final MFMA phase
        #pragma unroll
        for (int g = 0; g < 4; ++g)
            #pragma unroll
            for (int n = 0; n < 4; ++n)
                #pragma unroll
                for (int j = 0; j < 4; ++j)
                    xbuf[(n * 16 + fr) * 264 + wid * 64 + g * 16 + fg * 4 + j] =
                        (_Float16)acc[g][n][j];
        __syncthreads();
        int rr = t >> 2, c0 = (t & 3) * 64;     // rr = d, c0 = s_local base (64 elems/thread)
        size_t base = (((size_t)b0 * HH + h) * DH + rr) * SS + s0 + c0;
        #pragma unroll
        for (int q = 0; q < 8; ++q)
            *reinterpret_cast<uint4*>(vt + base + q * 8) =
                *reinterpret_cast<uint4*>(&xbuf[rr * 264 + c0 + q * 8]);
    } else {
        #pragma unroll
        for (int g = 0; g < 4; ++g)
            #pragma unroll
            for (int n = 0; n < 4; ++n)
                #pragma unroll
                for (int j = 0; j < 4; ++j) {
                    int row = wid * 64 + g * 16 + fg * 4 + j;
                    size_t idx = (((size_t)b0 * HH + h) * SS + s0 + row) * DH + n * 16 + fr;
                    float val = acc[g][n][j];
                    if (which == 0) val *= 0.125f;   // fold 1/sqrt(D) into Q (exact pow2)
                    _Float16 hi, lo;
                    splith(val, hi, lo);
                    if (which == 0) { qh[idx] = hi; ql[idx] = lo; }
                    else            { kh[idx] = hi; kl[idx] = lo; }
                }
    }
}

// ---------------------------------------------------------------
// attn (r15-identical): 32x32x16 MFMA, swapped QK^T, O^T = V^T.P.
// 3-term scores (kh*qh + kh*ql + kl*qh). Block = 128 q-rows,
// 4 waves x 32 q-cols, kv tiles of 64. Softmax lane-local;
// P in registers via packh2 + permlane32_swap. grid 768, XCD-swizzled.
// ---------------------------------------------------------------
__global__ __launch_bounds__(256, 3) void attn_kernel(
    const _Float16* __restrict__ qhp, const _Float16* __restrict__ qlp,
    const _Float16* __restrict__ khp, const _Float16* __restrict__ klp,
    const _Float16* __restrict__ vtp,
    _Float16* __restrict__ z)
{
    const int flat = blockIdx.x;
    const int remap = (flat & 7) * 96 + (flat >> 3);   // bijective, 768 = 8*96
    const int qt = remap & 15;                          // 16 tiles of 128 q-rows
    const int h  = (remap >> 4) % HH;
    const int b  = remap / (16 * HH);

    const size_t headbase = ((size_t)b * HH + h) * (size_t)(SS * DH);
    const _Float16* Qh = qhp + headbase;
    const _Float16* Ql = qlp + headbase;
    const _Float16* Kh = khp + headbase;
    const _Float16* Kl = klp + headbase;
    const _Float16* Vt = vtp + headbase;   // [d][s]

    __shared__ _Float16 ksh[64][68], ksl[64][68], vts[64][68];

    const int t = threadIdx.x;
    const int lane = t & 63, w = t >> 6;
    const int qcol = lane & 31, hi = lane >> 5;
    const int r4 = t >> 2, c16 = (t & 3) * 16;

    // Q B-frags (B[k=d][n=q]): lane holds Q[q = qt*128 + w*32 + qcol][d = hi*8 + j + 16ks]
    const size_t qbase = (size_t)(qt * 128 + w * 32 + qcol) * DH + hi * 8;
    f16x8 bqh[4], bql[4];
    #pragma unroll
    for (int ks = 0; ks < 4; ++ks) {
        bqh[ks] = *reinterpret_cast<const f16x8*>(Qh + qbase + 16 * ks);
        bql[ks] = *reinterpret_cast<const f16x8*>(Ql + qbase + 16 * ks);
    }

    uint4 rk0, rk1, rl0, rl1, rv0, rv1;
    auto prefetch = [&](int kt) {
        size_t sk = (size_t)(kt * 64 + r4) * DH + c16;
        rk0 = *reinterpret_cast<const uint4*>(Kh + sk);
        rk1 = *reinterpret_cast<const uint4*>(Kh + sk + 8);
        rl0 = *reinterpret_cast<const uint4*>(Kl + sk);
        rl1 = *reinterpret_cast<const uint4*>(Kl + sk + 8);
        size_t sv = (size_t)r4 * SS + kt * 64 + c16;
        rv0 = *reinterpret_cast<const uint4*>(Vt + sv);
        rv1 = *reinterpret_cast<const uint4*>(Vt + sv + 8);
    };
    prefetch(0);

    float mrun = -INFINITY, lrun = 0.f;    // per-lane: lane owns q-row qcol
    f32x16 oc0 = zero16(), oc1 = zero16(); // O^T: d 0-31 / d 32-63, col = q

    for (int kt = 0; kt < NT; ++kt) {
        __syncthreads();   // prior compute done reading ksh/ksl/vts
        stb64x2(&ksh[r4][c16],     rk0);
        stb64x2(&ksh[r4][c16 + 8], rk1);
        stb64x2(&ksl[r4][c16],     rl0);
        stb64x2(&ksl[r4][c16 + 8], rl1);
        stb64x2(&vts[r4][c16],     rv0);
        stb64x2(&vts[r4][c16 + 8], rv1);
        if (kt + 1 < NT) prefetch(kt + 1);
        __syncthreads();   // tile ready

        // ---- S^T = K.Q^T  (kh*qh + kh*ql + kl*qh), 24 MFMA 32x32x16 ----
        f32x16 c0 = zero16(), c1 = zero16();   // kv 0-31 / kv 32-63, col = q
        #pragma unroll
        for (int ks = 0; ks < 4; ++ks) {
            const int doff = hi * 8 + 16 * ks;
            f16x8 a0h = ldb64x2(&ksh[qcol][doff]);
            f16x8 a0l = ldb64x2(&ksl[qcol][doff]);
            c0 = __builtin_amdgcn_mfma_f32_32x32x16_f16(a0h, bqh[ks], c0, 0, 0, 0);
            c0 = __builtin_amdgcn_mfma_f32_32x32x16_f16(a0h, bql[ks], c0, 0, 0, 0);
            c0 = __builtin_amdgcn_mfma_f32_32x32x16_f16(a0l, bqh[ks], c0, 0, 0, 0);
            f16x8 a1h = ldb64x2(&ksh[qcol + 32][doff]);
            f16x8 a1l = ldb64x2(&ksl[qcol + 32][doff]);
            c1 = __builtin_amdgcn_mfma_f32_32x32x16_f16(a1h, bqh[ks], c1, 0, 0, 0);
            c1 = __builtin_amdgcn_mfma_f32_32x32x16_f16(a1h, bql[ks], c1, 0, 0, 0);
            c1 = __builtin_amdgcn_mfma_f32_32x32x16_f16(a1l, bqh[ks], c1, 0, 0, 0);
        }

        // ---- softmax: lane-local over its q-row (scores pre-scaled) ----
        float mx = c0[0];
        #pragma unroll
        for (int i = 1; i < 16; ++i) mx = fmaxf(mx, c0[i]);
        #pragma unroll
        for (int i = 0; i < 16; ++i) mx = fmaxf(mx, c1[i]);
        mx = fmaxf(mx, __shfl_xor(mx, 32));
        float nm = fmaxf(mrun, mx);
        float corr = __expf(mrun - nm);
        float sum = 0.f;
        #pragma unroll
        for (int i = 0; i < 16; ++i) { float p = __expf(c0[i] - nm); c0[i] = p; sum += p; }
        #pragma unroll
        for (int i = 0; i < 16; ++i) { float p = __expf(c1[i] - nm); c1[i] = p; sum += p; }
        sum += __shfl_xor(sum, 32);
        lrun = lrun * corr + sum;
        mrun = nm;
        #pragma unroll
        for (int i = 0; i < 16; ++i) { oc0[i] *= corr; oc1[i] *= corr; }

        // ---- P -> PV B-frags in registers (packh2 + permlane32_swap) ----
        auto mk = [](float s0, float s1, float s2, float s3,
                     float s4, float s5, float s6, float s7) -> f16x8 {
            unsigned a0 = packh2(s0, s1), a1 = packh2(s2, s3);
            unsigned b0 = packh2(s4, s5), b1 = packh2(s6, s7);
            asm volatile("v_permlane32_swap_b32 %0, %1" : "+v"(a0), "+v"(b0));
            asm volatile("v_permlane32_swap_b32 %0, %1" : "+v"(a1), "+v"(b1));
            u32x4 u = {a0, a1, b0, b1};
            return __builtin_bit_cast(f16x8, u);
        };
        f16x8 bp0 = mk(c0[0], c0[1], c0[2],  c0[3],  c0[4],  c0[5],  c0[6],  c0[7]);
        f16x8 bp1 = mk(c0[8], c0[9], c0[10], c0[11], c0[12], c0[13], c0[14], c0[15]);
        f16x8 bp2 = mk(c1[0], c1[1], c1[2],  c1[3],  c1[4],  c1[5],  c1[6],  c1[7]);
        f16x8 bp3 = mk(c1[8], c1[9], c1[10], c1[11], c1[12], c1[13], c1[14], c1[15]);

        // ---- O^T += V^T . P, 8 MFMA 32x32x16 ----
        {
            const int k0 = hi * 8;
            f16x8 av;
            av = ldb64x2(&vts[qcol][k0]);            oc0 = __builtin_amdgcn_mfma_f32_32x32x16_f16(av, bp0, oc0, 0, 0, 0);
            av = ldb64x2(&vts[qcol + 32][k0]);       oc1 = __builtin_amdgcn_mfma_f32_32x32x16_f16(av, bp0, oc1, 0, 0, 0);
            av = ldb64x2(&vts[qcol][k0 + 16]);       oc0 = __builtin_amdgcn_mfma_f32_32x32x16_f16(av, bp1, oc0, 0, 0, 0);
            av = ldb64x2(&vts[qcol + 32][k0 + 16]);  oc1 = __builtin_amdgcn_mfma_f32_32x32x16_f16(av, bp1, oc1, 0, 0, 0);
            av = ldb64x2(&vts[qcol][k0 + 32]);       oc0 = __builtin_amdgcn_mfma_f32_32x32x16_f16(av, bp2, oc0, 0, 0, 0);
            av = ldb64x2(&vts[qcol + 32][k0 + 32]);  oc1 = __builtin_amdgcn_mfma_f32_32x32x16_f16(av, bp2, oc1, 0, 0, 0);
            av = ldb64x2(&vts[qcol][k0 + 48]);       oc0 = __builtin_amdgcn_mfma_f32_32x32x16_f16(av, bp3, oc0, 0, 0, 0);
            av = ldb64x2(&vts[qcol + 32][k0 + 48]);  oc1 = __builtin_amdgcn_mfma_f32_32x32x16_f16(av, bp3, oc1, 0, 0, 0);
        }
    }

    // epilogue: O^T[d][q] regs -> z[b][s=q][h*64+d], scaled by 1/lrun
    float inv = 1.0f / lrun;
    size_t zb = ((size_t)b * SS + qt * 128 + w * 32 + qcol) * (size_t)(HH * DH) + h * DH;
    #pragma unroll
    for (int g = 0; g < 4; ++g) {
        f16x4 v0, v1;
        #pragma unroll
        for (int i = 0; i < 4; ++i) {
            v0[i] = (_Float16)(oc0[4 * g + i] * inv);
            v1[i] = (_Float16)(oc1[4 * g + i] * inv);
        }
        *reinterpret_cast<f16x4*>(z + zb + 8 * g + 4 * hi)      = v0;
        *reinterpret_cast<f16x4*>(z + zb + 32 + 8 * g + 4 * hi) = v1;
    }
}

// ---------------------------------------------------------------
// outproj: out[m][i] = sum_j wc[i][j] z[m][j]; z fp16, wc split fp16 2-term.
// grid 128, block 256.
// ---------------------------------------------------------------
__global__ __launch_bounds__(256) void outproj_kernel(
    const _Float16* __restrict__ z,
    const _Float16* __restrict__ wch, const _Float16* __restrict__ wcl,
    float* __restrict__ out)
{
    const int mt = blockIdx.x, m0 = mt * 64;
    __shared__ _Float16 zs[64][40], wh_[64][40], wl_[64][40];

    const int t = threadIdx.x;
    const int lane = t & 63, wid = t >> 6;
    const int fr = lane & 15, fg = lane >> 4, g8 = fg * 8;

    f32x4 acc[4];
    #pragma unroll
    for (int n = 0; n < 4; ++n) acc[n] = (f32x4){0.f, 0.f, 0.f, 0.f};

    for (int ks = 0; ks < DIN / 32; ++ks) {
        const int k0 = ks * 32;
        {
            int r = t >> 2, c8 = (t & 3) * 8;
            *reinterpret_cast<f16x8*>(&zs[r][c8]) =
                *reinterpret_cast<const f16x8*>(z + (size_t)(m0 + r) * DIN + k0 + c8);
            size_t wb = (size_t)r * DIN + k0 + c8;
            *reinterpret_cast<f16x8*>(&wh_[r][c8]) = *reinterpret_cast<const f16x8*>(wch + wb);
            *reinterpret_cast<f16x8*>(&wl_[r][c8]) = *reinterpret_cast<const f16x8*>(wcl + wb);
        }
        __syncthreads();
        f16x8 az = *reinterpret_cast<const f16x8*>(&zs[wid * 16 + fr][g8]);
        #pragma unroll
        for (int n = 0; n < 4; ++n) {
            f16x8 bh = *reinterpret_cast<const f16x8*>(&wh_[n * 16 + fr][g8]);
            f16x8 bl = *reinterpret_cast<const f16x8*>(&wl_[n * 16 + fr][g8]);
            acc[n] = __builtin_amdgcn_mfma_f32_16x16x32_f16(az, bh, acc[n], 0, 0, 0);
            acc[n] = __builtin_amdgcn_mfma_f32_16x16x32_f16(az, bl, acc[n], 0, 0, 0);
        }
        __syncthreads();
    }

    #pragma unroll
    for (int n = 0; n < 4; ++n)
        #pragma unroll
        for (int j = 0; j < 4; ++j) {
            int row = m0 + wid * 16 + fg * 4 + j;
            out[(size_t)row * DH + n * 16 + fr] = acc[n][j];
        }
}

extern "C" void kernel_launch(void* const* d_in, const int* in_sizes, int n_in,
                              void* d_out, int out_size, void* d_ws, size_t ws_size,
                              hipStream_t stream) {
    const float* x  = (const float*)d_in[0];
    const float* wq = (const float*)d_in[1];
    const float* wk = (const float*)d_in[2];
    const float* wv = (const float*)d_in[3];
    const float* wc = (const float*)d_in[4];
    float* out = (float*)d_out;

    const size_t wpl   = (size_t)3 * HH * 64 * DIN;     // 1,769,472
    const size_t plane = (size_t)BB * HH * SS * DH;     // 6,291,456
    _Float16* whi = (_Float16*)d_ws;
    _Float16* wlo = whi + wpl;
    _Float16* wch = wlo + wpl;
    _Float16* wcl = wch + (size_t)64 * DIN;
    _Float16* qh  = wcl + (size_t)64 * DIN;
    _Float16* ql  = qh + plane;
    _Float16* kh  = ql + plane;
    _Float16* kl  = kh + plane;
    _Float16* vt  = kl + plane;   // [b][h][d][s]
    // xh/xl alias the zz region: x split is dead before attn writes z.
    _Float16* xh  = vt + plane;
    _Float16* xl  = xh + plane;
    _Float16* zz  = xh;           // attn output overwrites xh (safe: qkv done)
    // total ws ~= 7.3MB (w) + 5*12.6MB + 25.2MB (xh/xl|zz) ~= 95.4MB

    prep_kernel<<<3528, 256, 0, stream>>>(x, wq, wk, wv, wc, whi, wlo, wch, wcl, xh, xl);
    qkv_proj_kernel<<<1152, 256, 0, stream>>>(xh, xl, whi, wlo, qh, ql, kh, kl, vt);
    attn_kernel<<<768, 256, 0, stream>>>(qh, ql, kh, kl, vt, zz);
    outproj_kernel<<<128, 256, 0, stream>>>(zz, wch, wcl, out);
}

// Round 23
// 239.167 us; speedup vs baseline: 1.7534x; 1.7534x over previous
//
#include <hip/hip_runtime.h>
#include <hip/hip_bf16.h>
#include <math.h>

#define BB 4
#define SS 2048
#define DIN 768
#define HH 12
#define DH 64
#define NT (SS / 64)

typedef __attribute__((ext_vector_type(8))) _Float16 f16x8;
typedef __attribute__((ext_vector_type(4))) _Float16 f16x4;
typedef __attribute__((ext_vector_type(2))) _Float16 f16x2;
typedef __attribute__((ext_vector_type(4))) float f32x4;
typedef __attribute__((ext_vector_type(16))) float f32x16;
typedef __attribute__((ext_vector_type(4))) unsigned u32x4;

// split fp32 -> fp16 hi + fp16 lo (v ~= hi+lo, |lo| <= 2^-11 |v|)
// r16 lesson: ALL lo-terms required (shared-mode error -> absmax 832).
// r20 lesson: LDS staging is a COALESCING transformer — per-lane direct
// B-frag loads touch 16 cache lines/instr and lose 2x (124->270us).
// r22 lesson: BM=256 spills (VGPR cap 112 < ~150 live) -> 9x write amp.
__device__ inline void splith(float v, _Float16& hi, _Float16& lo) {
    hi = (_Float16)v;
    lo = (_Float16)(v - (float)hi);
}
__device__ inline unsigned packh2(float a, float b) {
    f16x2 h; h[0] = (_Float16)a; h[1] = (_Float16)b;
    return __builtin_bit_cast(unsigned, h);
}
// 16B fp16 fragment via two 8B LDS reads (stride-68 rows are only 8B-aligned)
__device__ inline f16x8 ldb64x2(const _Float16* p) {
    const uint2* q = reinterpret_cast<const uint2*>(p);
    uint2 a = q[0], b = q[1];
    u32x4 u = {a.x, a.y, b.x, b.y};
    return __builtin_bit_cast(f16x8, u);
}
__device__ inline void stb64x2(_Float16* p, uint4 v) {
    uint2* q = reinterpret_cast<uint2*>(p);
    q[0] = make_uint2(v.x, v.y);
    q[1] = make_uint2(v.z, v.w);
}
__device__ inline f32x16 zero16() {
    f32x16 v;
    #pragma unroll
    for (int i = 0; i < 16; ++i) v[i] = 0.f;
    return v;
}

// ---------------------------------------------------------------
// prep (merged, one dispatch): [0,432) W split+transpose;
// [432,456) wc split; [456,3528) x -> fp16 hi AND lo.
// ---------------------------------------------------------------
__global__ __launch_bounds__(256) void prep_kernel(
    const float* __restrict__ x,
    const float* __restrict__ wq, const float* __restrict__ wk, const float* __restrict__ wv,
    const float* __restrict__ wc,
    _Float16* __restrict__ whi, _Float16* __restrict__ wlo,
    _Float16* __restrict__ wch, _Float16* __restrict__ wcl,
    _Float16* __restrict__ xh, _Float16* __restrict__ xl)
{
    __shared__ float tile[64][65];
    const int bid = blockIdx.x;
    const int t = threadIdx.x;

    if (bid < 432) {        // ---- W: [h][k][n] fp32 -> [plane][n][k] fp16 hi/lo
        const int kt = bid % 12, h = (bid / 12) % 12, which = bid / 144;
        const float* w = (which == 0) ? wq : (which == 1) ? wk : wv;
        w += (size_t)h * (DIN * DH);
        const size_t plane = ((size_t)which * HH + h) * (size_t)(64 * DIN);
        {
            int r = t >> 2, n0 = (t & 3) * 16;
            const float* src = w + (size_t)(kt * 64 + r) * DH + n0;
            #pragma unroll
            for (int q = 0; q < 4; ++q) {
                float4 v = *reinterpret_cast<const float4*>(src + q * 4);
                tile[r][n0 + q * 4 + 0] = v.x; tile[r][n0 + q * 4 + 1] = v.y;
                tile[r][n0 + q * 4 + 2] = v.z; tile[r][n0 + q * 4 + 3] = v.w;
            }
        }
        __syncthreads();
        {
            int n = t >> 2, k0 = (t & 3) * 16;
            f16x8 h0, h1, l0, l1;
            #pragma unroll
            for (int j = 0; j < 8; ++j) {
                _Float16 hh, ll;
                splith(tile[k0 + j][n], hh, ll);     h0[j] = hh; l0[j] = ll;
                splith(tile[k0 + 8 + j][n], hh, ll); h1[j] = hh; l1[j] = ll;
            }
            size_t base = plane + (size_t)n * DIN + kt * 64 + k0;
            *reinterpret_cast<f16x8*>(whi + base)     = h0;
            *reinterpret_cast<f16x8*>(whi + base + 8) = h1;
            *reinterpret_cast<f16x8*>(wlo + base)     = l0;
            *reinterpret_cast<f16x8*>(wlo + base + 8) = l1;
        }
    } else if (bid < 456) { // ---- wc split
        int idx = ((bid - 432) * 256 + t) * 8;
        float4 a = *reinterpret_cast<const float4*>(wc + idx);
        float4 b = *reinterpret_cast<const float4*>(wc + idx + 4);
        float f[8] = {a.x, a.y, a.z, a.w, b.x, b.y, b.z, b.w};
        f16x8 hv, lv;
        #pragma unroll
        for (int j = 0; j < 8; ++j) {
            _Float16 hh, ll;
            splith(f[j], hh, ll);
            hv[j] = hh; lv[j] = ll;
        }
        *reinterpret_cast<f16x8*>(wch + idx) = hv;
        *reinterpret_cast<f16x8*>(wcl + idx) = lv;
    } else {                // ---- x -> fp16 hi + lo
        int idx = ((bid - 456) * 256 + t) * 8;
        float4 a = *reinterpret_cast<const float4*>(x + idx);
        float4 b = *reinterpret_cast<const float4*>(x + idx + 4);
        float f[8] = {a.x, a.y, a.z, a.w, b.x, b.y, b.z, b.w};
        f16x8 hv, lv;
        #pragma unroll
        for (int j = 0; j < 8; ++j) {
            _Float16 hh, ll;
            splith(f[j], hh, ll);
            hv[j] = hh; lv[j] = ll;
        }
        *reinterpret_cast<f16x8*>(xh + idx) = hv;
        *reinterpret_cast<f16x8*>(xl + idx) = lv;
    }
}

// ---------------------------------------------------------------
// qkv_proj (r19, measured optimum of the 9-variant structure search):
// unmerged plane-per-block, BM=128, 3-term split. x LDS-staged with
// reg-prefetch of all 6 staging uint4 one k-tile ahead; w LDS-staged.
// grid 2304 = 8 xcd x 8 mt x 36 planes (x slice L2-resident per XCD).
// ---------------------------------------------------------------
__global__ __launch_bounds__(256) void qkv_proj_kernel(
    const _Float16* __restrict__ xh, const _Float16* __restrict__ xl,
    const _Float16* __restrict__ whi, const _Float16* __restrict__ wlo,
    _Float16* __restrict__ qh, _Float16* __restrict__ ql,
    _Float16* __restrict__ kh, _Float16* __restrict__ kl,
    _Float16* __restrict__ vt)
{
    const int flat = blockIdx.x;
    const int xcd  = flat & 7;
    const int rest = flat >> 3;             // 0..287
    const int mt   = xcd * 8 + (rest & 7);  // 0..63 (128-row tiles)
    const int hw   = rest >> 3;             // 0..35
    const int which = hw / HH, h = hw % HH;
    const int m0 = mt * 128;
    const size_t wplane = ((size_t)which * HH + h) * (size_t)(64 * DIN);

    // xbuf: [0..5119] = xsh[128][40], [5120..10239] = xsl[128][40];
    // epilogue reuses the same storage as vtile[64][136] (8704 <= 10240).
    __shared__ _Float16 xbuf[10240];
    __shared__ _Float16 wsh[64][40], wsl[64][40];

    const int t = threadIdx.x;
    const int lane = t & 63, wid = t >> 6;
    const int fr = lane & 15, fg = lane >> 4, g8 = fg * 8;
    const int rx = t >> 1, cbx = (t & 1) * 16;   // x-staging ownership
    const int rw = t >> 2, c8 = (t & 3) * 8;     // w-staging ownership

    f32x4 acc[2][4];
    #pragma unroll
    for (int g = 0; g < 2; ++g)
        #pragma unroll
        for (int n = 0; n < 4; ++n) acc[g][n] = (f32x4){0.f, 0.f, 0.f, 0.f};

    uint4 ph0, ph1, pl0, pl1, pwh, pwl;
    auto pre = [&](int ks) {
        const size_t xb = (size_t)(m0 + rx) * DIN + ks * 32 + cbx;
        ph0 = *reinterpret_cast<const uint4*>(xh + xb);
        ph1 = *reinterpret_cast<const uint4*>(xh + xb + 8);
        pl0 = *reinterpret_cast<const uint4*>(xl + xb);
        pl1 = *reinterpret_cast<const uint4*>(xl + xb + 8);
        const size_t wb = wplane + (size_t)rw * DIN + ks * 32 + c8;
        pwh = *reinterpret_cast<const uint4*>(whi + wb);
        pwl = *reinterpret_cast<const uint4*>(wlo + wb);
    };
    pre(0);

    for (int ks = 0; ks < DIN / 32; ++ks) {
        __syncthreads();   // prior MFMA phase done reading LDS
        *reinterpret_cast<uint4*>(&xbuf[rx * 40 + cbx])            = ph0;
        *reinterpret_cast<uint4*>(&xbuf[rx * 40 + cbx + 8])        = ph1;
        *reinterpret_cast<uint4*>(&xbuf[5120 + rx * 40 + cbx])     = pl0;
        *reinterpret_cast<uint4*>(&xbuf[5120 + rx * 40 + cbx + 8]) = pl1;
        *reinterpret_cast<uint4*>(&wsh[rw][c8]) = pwh;
        *reinterpret_cast<uint4*>(&wsl[rw][c8]) = pwl;
        if (ks + 1 < DIN / 32) pre(ks + 1);   // drains under MFMA below
        __syncthreads();   // tile ready

        f16x8 ah0 = *reinterpret_cast<const f16x8*>(&xbuf[(wid * 32 + fr) * 40 + g8]);
        f16x8 al0 = *reinterpret_cast<const f16x8*>(&xbuf[5120 + (wid * 32 + fr) * 40 + g8]);
        f16x8 ah1 = *reinterpret_cast<const f16x8*>(&xbuf[(wid * 32 + 16 + fr) * 40 + g8]);
        f16x8 al1 = *reinterpret_cast<const f16x8*>(&xbuf[5120 + (wid * 32 + 16 + fr) * 40 + g8]);
        #pragma unroll
        for (int n = 0; n < 4; ++n) {
            f16x8 bh = *reinterpret_cast<const f16x8*>(&wsh[n * 16 + fr][g8]);
            f16x8 bl = *reinterpret_cast<const f16x8*>(&wsl[n * 16 + fr][g8]);
            acc[0][n] = __builtin_amdgcn_mfma_f32_16x16x32_f16(ah0, bh, acc[0][n], 0, 0, 0);
            acc[0][n] = __builtin_amdgcn_mfma_f32_16x16x32_f16(ah0, bl, acc[0][n], 0, 0, 0);
            acc[0][n] = __builtin_amdgcn_mfma_f32_16x16x32_f16(al0, bh, acc[0][n], 0, 0, 0);
            acc[1][n] = __builtin_amdgcn_mfma_f32_16x16x32_f16(ah1, bh, acc[1][n], 0, 0, 0);
            acc[1][n] = __builtin_amdgcn_mfma_f32_16x16x32_f16(ah1, bl, acc[1][n], 0, 0, 0);
            acc[1][n] = __builtin_amdgcn_mfma_f32_16x16x32_f16(al1, bh, acc[1][n], 0, 0, 0);
        }
    }

    const int b0 = m0 >> 11, s0 = m0 & 2047;   // 128-row tile stays within one batch
    if (which == 2) {
        // V -> vtile[d][s_local] (overlays xbuf) then vector row-stores
        __syncthreads();   // all waves done reading xbuf in final MFMA phase
        #pragma unroll
        for (int g = 0; g < 2; ++g)
            #pragma unroll
            for (int n = 0; n < 4; ++n)
                #pragma unroll
                for (int j = 0; j < 4; ++j)
                    xbuf[(n * 16 + fr) * 136 + wid * 32 + g * 16 + fg * 4 + j] =
                        (_Float16)acc[g][n][j];
        __syncthreads();
        int rr = t >> 2, c0 = (t & 3) * 32;     // rr = d, c0 = s_local base (32 elems/thread)
        size_t base = (((size_t)b0 * HH + h) * DH + rr) * SS + s0 + c0;
        #pragma unroll
        for (int q = 0; q < 4; ++q)
            *reinterpret_cast<uint4*>(vt + base + q * 8) =
                *reinterpret_cast<uint4*>(&xbuf[rr * 136 + c0 + q * 8]);
    } else {
        #pragma unroll
        for (int g = 0; g < 2; ++g)
            #pragma unroll
            for (int n = 0; n < 4; ++n)
                #pragma unroll
                for (int j = 0; j < 4; ++j) {
                    int row = wid * 32 + g * 16 + fg * 4 + j;
                    size_t idx = (((size_t)b0 * HH + h) * SS + s0 + row) * DH + n * 16 + fr;
                    float val = acc[g][n][j];
                    if (which == 0) val *= 0.125f;   // fold 1/sqrt(D) into Q (exact pow2)
                    _Float16 hi, lo;
                    splith(val, hi, lo);
                    if (which == 0) { qh[idx] = hi; ql[idx] = lo; }
                    else            { kh[idx] = hi; kl[idx] = lo; }
                }
    }
}

// ---------------------------------------------------------------
// attn (r15-identical): 32x32x16 MFMA, swapped QK^T, O^T = V^T.P.
// 3-term scores (kh*qh + kh*ql + kl*qh). Block = 128 q-rows,
// 4 waves x 32 q-cols, kv tiles of 64. Softmax lane-local;
// P in registers via packh2 + permlane32_swap. grid 768, XCD-swizzled.
// ---------------------------------------------------------------
__global__ __launch_bounds__(256, 3) void attn_kernel(
    const _Float16* __restrict__ qhp, const _Float16* __restrict__ qlp,
    const _Float16* __restrict__ khp, const _Float16* __restrict__ klp,
    const _Float16* __restrict__ vtp,
    _Float16* __restrict__ z)
{
    const int flat = blockIdx.x;
    const int remap = (flat & 7) * 96 + (flat >> 3);   // bijective, 768 = 8*96
    const int qt = remap & 15;                          // 16 tiles of 128 q-rows
    const int h  = (remap >> 4) % HH;
    const int b  = remap / (16 * HH);

    const size_t headbase = ((size_t)b * HH + h) * (size_t)(SS * DH);
    const _Float16* Qh = qhp + headbase;
    const _Float16* Ql = qlp + headbase;
    const _Float16* Kh = khp + headbase;
    const _Float16* Kl = klp + headbase;
    const _Float16* Vt = vtp + headbase;   // [d][s]

    __shared__ _Float16 ksh[64][68], ksl[64][68], vts[64][68];

    const int t = threadIdx.x;
    const int lane = t & 63, w = t >> 6;
    const int qcol = lane & 31, hi = lane >> 5;
    const int r4 = t >> 2, c16 = (t & 3) * 16;

    // Q B-frags (B[k=d][n=q]): lane holds Q[q = qt*128 + w*32 + qcol][d = hi*8 + j + 16ks]
    const size_t qbase = (size_t)(qt * 128 + w * 32 + qcol) * DH + hi * 8;
    f16x8 bqh[4], bql[4];
    #pragma unroll
    for (int ks = 0; ks < 4; ++ks) {
        bqh[ks] = *reinterpret_cast<const f16x8*>(Qh + qbase + 16 * ks);
        bql[ks] = *reinterpret_cast<const f16x8*>(Ql + qbase + 16 * ks);
    }

    uint4 rk0, rk1, rl0, rl1, rv0, rv1;
    auto prefetch = [&](int kt) {
        size_t sk = (size_t)(kt * 64 + r4) * DH + c16;
        rk0 = *reinterpret_cast<const uint4*>(Kh + sk);
        rk1 = *reinterpret_cast<const uint4*>(Kh + sk + 8);
        rl0 = *reinterpret_cast<const uint4*>(Kl + sk);
        rl1 = *reinterpret_cast<const uint4*>(Kl + sk + 8);
        size_t sv = (size_t)r4 * SS + kt * 64 + c16;
        rv0 = *reinterpret_cast<const uint4*>(Vt + sv);
        rv1 = *reinterpret_cast<const uint4*>(Vt + sv + 8);
    };
    prefetch(0);

    float mrun = -INFINITY, lrun = 0.f;    // per-lane: lane owns q-row qcol
    f32x16 oc0 = zero16(), oc1 = zero16(); // O^T: d 0-31 / d 32-63, col = q

    for (int kt = 0; kt < NT; ++kt) {
        __syncthreads();   // prior compute done reading ksh/ksl/vts
        stb64x2(&ksh[r4][c16],     rk0);
        stb64x2(&ksh[r4][c16 + 8], rk1);
        stb64x2(&ksl[r4][c16],     rl0);
        stb64x2(&ksl[r4][c16 + 8], rl1);
        stb64x2(&vts[r4][c16],     rv0);
        stb64x2(&vts[r4][c16 + 8], rv1);
        if (kt + 1 < NT) prefetch(kt + 1);
        __syncthreads();   // tile ready

        // ---- S^T = K.Q^T  (kh*qh + kh*ql + kl*qh), 24 MFMA 32x32x16 ----
        f32x16 c0 = zero16(), c1 = zero16();   // kv 0-31 / kv 32-63, col = q
        #pragma unroll
        for (int ks = 0; ks < 4; ++ks) {
            const int doff = hi * 8 + 16 * ks;
            f16x8 a0h = ldb64x2(&ksh[qcol][doff]);
            f16x8 a0l = ldb64x2(&ksl[qcol][doff]);
            c0 = __builtin_amdgcn_mfma_f32_32x32x16_f16(a0h, bqh[ks], c0, 0, 0, 0);
            c0 = __builtin_amdgcn_mfma_f32_32x32x16_f16(a0h, bql[ks], c0, 0, 0, 0);
            c0 = __builtin_amdgcn_mfma_f32_32x32x16_f16(a0l, bqh[ks], c0, 0, 0, 0);
            f16x8 a1h = ldb64x2(&ksh[qcol + 32][doff]);
            f16x8 a1l = ldb64x2(&ksl[qcol + 32][doff]);
            c1 = __builtin_amdgcn_mfma_f32_32x32x16_f16(a1h, bqh[ks], c1, 0, 0, 0);
            c1 = __builtin_amdgcn_mfma_f32_32x32x16_f16(a1h, bql[ks], c1, 0, 0, 0);
            c1 = __builtin_amdgcn_mfma_f32_32x32x16_f16(a1l, bqh[ks], c1, 0, 0, 0);
        }

        // ---- softmax: lane-local over its q-row (scores pre-scaled) ----
        float mx = c0[0];
        #pragma unroll
        for (int i = 1; i < 16; ++i) mx = fmaxf(mx, c0[i]);
        #pragma unroll
        for (int i = 0; i < 16; ++i) mx = fmaxf(mx, c1[i]);
        mx = fmaxf(mx, __shfl_xor(mx, 32));
        float nm = fmaxf(mrun, mx);
        float corr = __expf(mrun - nm);
        float sum = 0.f;
        #pragma unroll
        for (int i = 0; i < 16; ++i) { float p = __expf(c0[i] - nm); c0[i] = p; sum += p; }
        #pragma unroll
        for (int i = 0; i < 16; ++i) { float p = __expf(c1[i] - nm); c1[i] = p; sum += p; }
        sum += __shfl_xor(sum, 32);
        lrun = lrun * corr + sum;
        mrun = nm;
        #pragma unroll
        for (int i = 0; i < 16; ++i) { oc0[i] *= corr; oc1[i] *= corr; }

        // ---- P -> PV B-frags in registers (packh2 + permlane32_swap) ----
        auto mk = [](float s0, float s1, float s2, float s3,
                     float s4, float s5, float s6, float s7) -> f16x8 {
            unsigned a0 = packh2(s0, s1), a1 = packh2(s2, s3);
            unsigned b0 = packh2(s4, s5), b1 = packh2(s6, s7);
            asm volatile("v_permlane32_swap_b32 %0, %1" : "+v"(a0), "+v"(b0));
            asm volatile("v_permlane32_swap_b32 %0, %1" : "+v"(a1), "+v"(b1));
            u32x4 u = {a0, a1, b0, b1};
            return __builtin_bit_cast(f16x8, u);
        };
        f16x8 bp0 = mk(c0[0], c0[1], c0[2],  c0[3],  c0[4],  c0[5],  c0[6],  c0[7]);
        f16x8 bp1 = mk(c0[8], c0[9], c0[10], c0[11], c0[12], c0[13], c0[14], c0[15]);
        f16x8 bp2 = mk(c1[0], c1[1], c1[2],  c1[3],  c1[4],  c1[5],  c1[6],  c1[7]);
        f16x8 bp3 = mk(c1[8], c1[9], c1[10], c1[11], c1[12], c1[13], c1[14], c1[15]);

        // ---- O^T += V^T . P, 8 MFMA 32x32x16 ----
        {
            const int k0 = hi * 8;
            f16x8 av;
            av = ldb64x2(&vts[qcol][k0]);            oc0 = __builtin_amdgcn_mfma_f32_32x32x16_f16(av, bp0, oc0, 0, 0, 0);
            av = ldb64x2(&vts[qcol + 32][k0]);       oc1 = __builtin_amdgcn_mfma_f32_32x32x16_f16(av, bp0, oc1, 0, 0, 0);
            av = ldb64x2(&vts[qcol][k0 + 16]);       oc0 = __builtin_amdgcn_mfma_f32_32x32x16_f16(av, bp1, oc0, 0, 0, 0);
            av = ldb64x2(&vts[qcol + 32][k0 + 16]);  oc1 = __builtin_amdgcn_mfma_f32_32x32x16_f16(av, bp1, oc1, 0, 0, 0);
            av = ldb64x2(&vts[qcol][k0 + 32]);       oc0 = __builtin_amdgcn_mfma_f32_32x32x16_f16(av, bp2, oc0, 0, 0, 0);
            av = ldb64x2(&vts[qcol + 32][k0 + 32]);  oc1 = __builtin_amdgcn_mfma_f32_32x32x16_f16(av, bp2, oc1, 0, 0, 0);
            av = ldb64x2(&vts[qcol][k0 + 48]);       oc0 = __builtin_amdgcn_mfma_f32_32x32x16_f16(av, bp3, oc0, 0, 0, 0);
            av = ldb64x2(&vts[qcol + 32][k0 + 48]);  oc1 = __builtin_amdgcn_mfma_f32_32x32x16_f16(av, bp3, oc1, 0, 0, 0);
        }
    }

    // epilogue: O^T[d][q] regs -> z[b][s=q][h*64+d], scaled by 1/lrun
    float inv = 1.0f / lrun;
    size_t zb = ((size_t)b * SS + qt * 128 + w * 32 + qcol) * (size_t)(HH * DH) + h * DH;
    #pragma unroll
    for (int g = 0; g < 4; ++g) {
        f16x4 v0, v1;
        #pragma unroll
        for (int i = 0; i < 4; ++i) {
            v0[i] = (_Float16)(oc0[4 * g + i] * inv);
            v1[i] = (_Float16)(oc1[4 * g + i] * inv);
        }
        *reinterpret_cast<f16x4*>(z + zb + 8 * g + 4 * hi)      = v0;
        *reinterpret_cast<f16x4*>(z + zb + 32 + 8 * g + 4 * hi) = v1;
    }
}

// ---------------------------------------------------------------
// outproj: out[m][i] = sum_j wc[i][j] z[m][j]; z fp16, wc split fp16 2-term.
// grid 128, block 256.
// ---------------------------------------------------------------
__global__ __launch_bounds__(256) void outproj_kernel(
    const _Float16* __restrict__ z,
    const _Float16* __restrict__ wch, const _Float16* __restrict__ wcl,
    float* __restrict__ out)
{
    const int mt = blockIdx.x, m0 = mt * 64;
    __shared__ _Float16 zs[64][40], wh_[64][40], wl_[64][40];

    const int t = threadIdx.x;
    const int lane = t & 63, wid = t >> 6;
    const int fr = lane & 15, fg = lane >> 4, g8 = fg * 8;

    f32x4 acc[4];
    #pragma unroll
    for (int n = 0; n < 4; ++n) acc[n] = (f32x4){0.f, 0.f, 0.f, 0.f};

    for (int ks = 0; ks < DIN / 32; ++ks) {
        const int k0 = ks * 32;
        {
            int r = t >> 2, c8 = (t & 3) * 8;
            *reinterpret_cast<f16x8*>(&zs[r][c8]) =
                *reinterpret_cast<const f16x8*>(z + (size_t)(m0 + r) * DIN + k0 + c8);
            size_t wb = (size_t)r * DIN + k0 + c8;
            *reinterpret_cast<f16x8*>(&wh_[r][c8]) = *reinterpret_cast<const f16x8*>(wch + wb);
            *reinterpret_cast<f16x8*>(&wl_[r][c8]) = *reinterpret_cast<const f16x8*>(wcl + wb);
        }
        __syncthreads();
        f16x8 az = *reinterpret_cast<const f16x8*>(&zs[wid * 16 + fr][g8]);
        #pragma unroll
        for (int n = 0; n < 4; ++n) {
            f16x8 bh = *reinterpret_cast<const f16x8*>(&wh_[n * 16 + fr][g8]);
            f16x8 bl = *reinterpret_cast<const f16x8*>(&wl_[n * 16 + fr][g8]);
            acc[n] = __builtin_amdgcn_mfma_f32_16x16x32_f16(az, bh, acc[n], 0, 0, 0);
            acc[n] = __builtin_amdgcn_mfma_f32_16x16x32_f16(az, bl, acc[n], 0, 0, 0);
        }
        __syncthreads();
    }

    #pragma unroll
    for (int n = 0; n < 4; ++n)
        #pragma unroll
        for (int j = 0; j < 4; ++j) {
            int row = m0 + wid * 16 + fg * 4 + j;
            out[(size_t)row * DH + n * 16 + fr] = acc[n][j];
        }
}

extern "C" void kernel_launch(void* const* d_in, const int* in_sizes, int n_in,
                              void* d_out, int out_size, void* d_ws, size_t ws_size,
                              hipStream_t stream) {
    const float* x  = (const float*)d_in[0];
    const float* wq = (const float*)d_in[1];
    const float* wk = (const float*)d_in[2];
    const float* wv = (const float*)d_in[3];
    const float* wc = (const float*)d_in[4];
    float* out = (float*)d_out;

    const size_t wpl   = (size_t)3 * HH * 64 * DIN;     // 1,769,472
    const size_t plane = (size_t)BB * HH * SS * DH;     // 6,291,456
    _Float16* whi = (_Float16*)d_ws;
    _Float16* wlo = whi + wpl;
    _Float16* wch = wlo + wpl;
    _Float16* wcl = wch + (size_t)64 * DIN;
    _Float16* qh  = wcl + (size_t)64 * DIN;
    _Float16* ql  = qh + plane;
    _Float16* kh  = ql + plane;
    _Float16* kl  = kh + plane;
    _Float16* vt  = kl + plane;   // [b][h][d][s]
    // xh/xl alias the zz region: x split is dead before attn writes z.
    _Float16* xh  = vt + plane;
    _Float16* xl  = xh + plane;
    _Float16* zz  = xh;           // attn output overwrites xh (safe: qkv done)
    // total ws ~= 7.3MB (w) + 5*12.6MB + 25.2MB (xh/xl|zz) ~= 95.4MB

    prep_kernel<<<3528, 256, 0, stream>>>(x, wq, wk, wv, wc, whi, wlo, wch, wcl, xh, xl);
    qkv_proj_kernel<<<2304, 256, 0, stream>>>(xh, xl, whi, wlo, qh, ql, kh, kl, vt);
    attn_kernel<<<768, 256, 0, stream>>>(qh, ql, kh, kl, vt, zz);
    outproj_kernel<<<128, 256, 0, stream>>>(zz, wch, wcl, out);
}